// Round 6
// baseline (425.259 us; speedup 1.0000x reference)
//
#include <hip/hip_runtime.h>
#include <hip/hip_bf16.h>
#include <stdint.h>

#define BATCH   32
#define SEQ     512
#define DMODEL  128
#define NHEADS  8
#define DHEAD   64
#define NEGV    -1e9f

using f32x4 = __attribute__((ext_vector_type(4))) float;
using s16x8 = __attribute__((ext_vector_type(8))) short;
using u16x4 = __attribute__((ext_vector_type(4))) unsigned short;
using u16x8 = __attribute__((ext_vector_type(8))) unsigned short;

__device__ __forceinline__ unsigned short f2bf(float f) {
    union { float f; unsigned int i; } w; w.f = f;
    unsigned int u = w.i;
    u += 0x7fffu + ((u >> 16) & 1u);   // RNE
    return (unsigned short)(u >> 16);
}
// Build an 8-bf16 MFMA fragment from two float4 global loads (fp32 source).
__device__ __forceinline__ s16x8 fragf(const float* p0, const float* p1) {
    float4 a = *reinterpret_cast<const float4*>(p0);
    float4 b = *reinterpret_cast<const float4*>(p1);
    union { s16x8 v; unsigned short e[8]; } u;
    u.e[0] = f2bf(a.x); u.e[1] = f2bf(a.y); u.e[2] = f2bf(a.z); u.e[3] = f2bf(a.w);
    u.e[4] = f2bf(b.x); u.e[5] = f2bf(b.y); u.e[6] = f2bf(b.z); u.e[7] = f2bf(b.w);
    return u.v;
}
// LDS bf16 fragment read with per-row XOR swizzle (element units; halves independent)
__device__ __forceinline__ s16x8 lds_frag(const unsigned short* row_base, int col0, int swz) {
    union { s16x8 v; u16x4 h[2]; } u;
    u.h[0] = *reinterpret_cast<const u16x4*>(row_base + ((col0) ^ swz));
    u.h[1] = *reinterpret_cast<const u16x4*>(row_base + ((col0 + 16) ^ swz));
    return u.v;
}

// ---------------- Kernel 0a: W_fc fp32 [512][128] -> Wtfc bf16 [128][512] ----------------
__global__ void wtrans_fc_kernel(const float* __restrict__ wfc,
                                 unsigned short* __restrict__ dst) {
    const int i0 = blockIdx.x * 8192;
    for (int i = i0 + threadIdx.x; i < i0 + 8192; i += 256) {
        int k = i >> 7, n = i & 127;
        dst[(size_t)n * 512 + k] = f2bf(wfc[i]);
    }
}

// ---------------- Kernel 0b: mask int32 -> bitpack (1 bit/elem, u64 per 64 keys) ----------
__global__ void mask_bitpack_kernel(const int* __restrict__ mask,
                                    unsigned long long* __restrict__ bits) {
    const int wave = threadIdx.x >> 6, lane = threadIdx.x & 63;
    const int wid0 = (blockIdx.x * 4 + wave) * 16;
#pragma unroll
    for (int i = 0; i < 16; i++) {
        const int w = wid0 + i;
        int v = mask[(size_t)w * 64 + lane];
        unsigned long long bb = __ballot(v != 0);
        if (lane == 0) bits[w] = bb;
    }
}

// ---------------- Kernel 1: fused per-(b,h) attention ----------------
__global__ __launch_bounds__(512, 1) void attn_mega_kernel(
    const float* __restrict__ inQ,   // [b*512][128] fp32
    const float* __restrict__ inK,
    const float* __restrict__ inV,
    const float* __restrict__ WQ,    // [128][512] fp32
    const float* __restrict__ WK,
    const float* __restrict__ WV,
    const unsigned long long* __restrict__ mbits, // [b*512][8] bitpacked mask
    float* __restrict__ attn_out,    // [bh][q][k] fp32
    unsigned short* __restrict__ ctx) { // [b*512][512] bf16 (ws)
    __shared__ unsigned short Klds[512 * 64];   // [s][d] swizzled
    __shared__ unsigned short Vlds[64 * 512];   // [d][s] swizzled
    __shared__ unsigned short Wt[64 * 128];     // [d][k] swizzled (staging, reused)

    const int tid  = threadIdx.x;
    const int lane = tid & 63;
    const int wave = tid >> 6;        // 0..7
    const int g = lane >> 4, c = lane & 15;
    // XCD-aware swizzle: XCD x (= bid&7) owns b in {4x..4x+3}, all heads.
    const int bid = blockIdx.x;
    const int bh = (((bid & 7) * 4 + ((bid >> 3) & 3)) << 3) + (bid >> 5);
    const int b = bh >> 3, h = bh & 7;
    const int col0 = 4 * g;

    // ---------- stage W_K^T (bf16, swizzled), project K into Klds ----------
    for (int i = tid; i < 8192; i += 512) {
        int k = i >> 6, d = i & 63;
        Wt[d * 128 + (k ^ ((d & 7) << 3))] = f2bf(WK[(size_t)k * 512 + h * 64 + d]);
    }
    __syncthreads();
    {
        f32x4 ka[4][4];   // [st][dt]
#pragma unroll
        for (int st = 0; st < 4; st++)
#pragma unroll
            for (int dt = 0; dt < 4; dt++) ka[st][dt] = f32x4{0.f, 0.f, 0.f, 0.f};
#pragma unroll
        for (int ks = 0; ks < 4; ks++) {
            s16x8 xk[4], wt[4];
#pragma unroll
            for (int st = 0; st < 4; st++) {
                const float* p = inK + (size_t)(b * 512 + wave * 64 + st * 16 + c) * 128 + ks * 32 + col0;
                xk[st] = fragf(p, p + 16);
            }
#pragma unroll
            for (int dt = 0; dt < 4; dt++) {
                int row = dt * 16 + c;
                wt[dt] = lds_frag(Wt + row * 128, ks * 32 + col0, (row & 7) << 3);
            }
#pragma unroll
            for (int st = 0; st < 4; st++)
#pragma unroll
                for (int dt = 0; dt < 4; dt++)
                    ka[st][dt] = __builtin_amdgcn_mfma_f32_16x16x32_bf16(wt[dt], xk[st], ka[st][dt], 0, 0, 0);
        }
#pragma unroll
        for (int st = 0; st < 4; st++) {
            const int s = wave * 64 + st * 16 + c;
            const int swz = (s & 7) << 3;
#pragma unroll
            for (int dt = 0; dt < 4; dt++) {
                u16x4 o;
#pragma unroll
                for (int j = 0; j < 4; j++) o[j] = f2bf(ka[st][dt][j]);
                *reinterpret_cast<u16x4*>(Klds + s * 64 + ((dt * 16 + col0) ^ swz)) = o;
            }
        }
    }
    __syncthreads();

    // ---------- stage W_V^T, project V into Vlds (transposed [d][s]) ----------
    for (int i = tid; i < 8192; i += 512) {
        int k = i >> 6, d = i & 63;
        Wt[d * 128 + (k ^ ((d & 7) << 3))] = f2bf(WV[(size_t)k * 512 + h * 64 + d]);
    }
    __syncthreads();
    {
        f32x4 va[4][4];
#pragma unroll
        for (int st = 0; st < 4; st++)
#pragma unroll
            for (int dt = 0; dt < 4; dt++) va[st][dt] = f32x4{0.f, 0.f, 0.f, 0.f};
#pragma unroll
        for (int ks = 0; ks < 4; ks++) {
            s16x8 xv[4], wt[4];
#pragma unroll
            for (int st = 0; st < 4; st++) {
                const float* p = inV + (size_t)(b * 512 + wave * 64 + st * 16 + c) * 128 + ks * 32 + col0;
                xv[st] = fragf(p, p + 16);
            }
#pragma unroll
            for (int dt = 0; dt < 4; dt++) {
                int row = dt * 16 + c;
                wt[dt] = lds_frag(Wt + row * 128, ks * 32 + col0, (row & 7) << 3);
            }
#pragma unroll
            for (int st = 0; st < 4; st++)
#pragma unroll
                for (int dt = 0; dt < 4; dt++)
                    va[st][dt] = __builtin_amdgcn_mfma_f32_16x16x32_bf16(xv[st], wt[dt], va[st][dt], 0, 0, 0);
        }
#pragma unroll
        for (int dt = 0; dt < 4; dt++) {
            const int d = dt * 16 + c;
            const int swz = (d & 7) << 3;
#pragma unroll
            for (int st = 0; st < 4; st++) {
                u16x4 o;
#pragma unroll
                for (int j = 0; j < 4; j++) o[j] = f2bf(va[st][dt][j]);
                *reinterpret_cast<u16x4*>(Vlds + d * 512 + ((wave * 64 + st * 16 + col0) ^ swz)) = o;
            }
        }
    }
    __syncthreads();

    // ---------- stage W_Q^T (stays resident) ----------
    for (int i = tid; i < 8192; i += 512) {
        int k = i >> 6, d = i & 63;
        Wt[d * 128 + (k ^ ((d & 7) << 3))] = f2bf(WQ[(size_t)k * 512 + h * 64 + d]);
    }
    __syncthreads();

    // ---------- 4 q-passes: 8 waves x 16 q each ----------
    for (int qp = 0; qp < 4; qp++) {
        const int qg = qp * 128 + wave * 16 + c;

        // mask bits for this q-row: full 64 bytes = 4 x uint4
        union { uint4 q[4]; unsigned short e[32]; } mb;
        {
            const unsigned short* mrow16 = (const unsigned short*)(mbits + ((size_t)b * 512 + qg) * 8);
            mb.q[0] = *reinterpret_cast<const uint4*>(mrow16);
            mb.q[1] = *reinterpret_cast<const uint4*>(mrow16 + 8);
            mb.q[2] = *reinterpret_cast<const uint4*>(mrow16 + 16);
            mb.q[3] = *reinterpret_cast<const uint4*>(mrow16 + 24);
        }

        // Q projection -> B-fragments of swapped QK^T
        f32x4 qa[4];
#pragma unroll
        for (int dt = 0; dt < 4; dt++) qa[dt] = f32x4{0.f, 0.f, 0.f, 0.f};
        const float* Xq = inQ + ((size_t)b * 512 + qg) * 128;
#pragma unroll
        for (int ks = 0; ks < 4; ks++) {
            s16x8 xq = fragf(Xq + ks * 32 + col0, Xq + ks * 32 + col0 + 16);
#pragma unroll
            for (int dt = 0; dt < 4; dt++) {
                int row = dt * 16 + c;
                s16x8 wt = lds_frag(Wt + row * 128, ks * 32 + col0, (row & 7) << 3);
                qa[dt] = __builtin_amdgcn_mfma_f32_16x16x32_bf16(wt, xq, qa[dt], 0, 0, 0);
            }
        }
        s16x8 qf0, qf1;
        {
            union { s16x8 v; u16x4 h2[2]; } q0, q1;
#pragma unroll
            for (int j = 0; j < 4; j++) {
                q0.h2[0][j] = f2bf(qa[0][j]);
                q0.h2[1][j] = f2bf(qa[1][j]);
                q1.h2[0][j] = f2bf(qa[2][j]);
                q1.h2[1][j] = f2bf(qa[3][j]);
            }
            qf0 = q0.v; qf1 = q1.v;
        }

        // S^T = K * Q^T : acc[kt][j] = score(key = kt*16 + 4g + j, q = qg)
        f32x4 acc[32];
#pragma unroll
        for (int t = 0; t < 32; t++) acc[t] = f32x4{0.f, 0.f, 0.f, 0.f};
#pragma unroll
        for (int kt = 0; kt < 32; kt++) {
            const int row = kt * 16 + c;
            const int swz = (row & 7) << 3;
            const unsigned short* rb = Klds + row * 64;
            s16x8 a0 = lds_frag(rb, col0, swz);
            s16x8 a1 = lds_frag(rb, 32 + col0, swz);
            acc[kt] = __builtin_amdgcn_mfma_f32_16x16x32_bf16(a0, qf0, acc[kt], 0, 0, 0);
            acc[kt] = __builtin_amdgcn_mfma_f32_16x16x32_bf16(a1, qf1, acc[kt], 0, 0, 0);
        }

        // scale + mask (from bits) + row max
        float m = -3.0e38f;
#pragma unroll
        for (int t = 0; t < 32; t++) {
            const unsigned nib = ((unsigned)mb.e[t]) >> col0;
            float s0 = (nib & 1u) ? NEGV : acc[t][0] * 0.125f;
            float s1 = (nib & 2u) ? NEGV : acc[t][1] * 0.125f;
            float s2 = (nib & 4u) ? NEGV : acc[t][2] * 0.125f;
            float s3 = (nib & 8u) ? NEGV : acc[t][3] * 0.125f;
            acc[t] = f32x4{s0, s1, s2, s3};
            m = fmaxf(m, fmaxf(fmaxf(s0, s1), fmaxf(s2, s3)));
        }
        m = fmaxf(m, __shfl_xor(m, 16));
        m = fmaxf(m, __shfl_xor(m, 32));

        float sum = 0.f;
#pragma unroll
        for (int t = 0; t < 32; t++) {
#pragma unroll
            for (int j = 0; j < 4; j++) {
                float e = __expf(acc[t][j] - m);
                acc[t][j] = e;
                sum += e;
            }
        }
        sum += __shfl_xor(sum, 16);
        sum += __shfl_xor(sum, 32);
        const float inv = 1.0f / sum;

        float* arow = attn_out + ((size_t)bh * 512 + qg) * 512;
        f32x4 cacc[4];
#pragma unroll
        for (int dt = 0; dt < 4; dt++) cacc[dt] = f32x4{0.f, 0.f, 0.f, 0.f};

#pragma unroll
        for (int kk = 0; kk < 16; kk++) {
            float4 flo, fhi;
            u16x4 lo, hi;
            flo.x = acc[2 * kk][0] * inv;  flo.y = acc[2 * kk][1] * inv;
            flo.z = acc[2 * kk][2] * inv;  flo.w = acc[2 * kk][3] * inv;
            fhi.x = acc[2 * kk + 1][0] * inv; fhi.y = acc[2 * kk + 1][1] * inv;
            fhi.z = acc[2 * kk + 1][2] * inv; fhi.w = acc[2 * kk + 1][3] * inv;
            lo[0] = f2bf(flo.x); lo[1] = f2bf(flo.y); lo[2] = f2bf(flo.z); lo[3] = f2bf(flo.w);
            hi[0] = f2bf(fhi.x); hi[1] = f2bf(fhi.y); hi[2] = f2bf(fhi.z); hi[3] = f2bf(fhi.w);
            *reinterpret_cast<float4*>(arow + kk * 32 + col0)      = flo;
            *reinterpret_cast<float4*>(arow + kk * 32 + 16 + col0) = fhi;
            union { s16x8 v; u16x4 h2[2]; } pf;
            pf.h2[0] = lo; pf.h2[1] = hi;
#pragma unroll
            for (int dt = 0; dt < 4; dt++) {
                const int d = dt * 16 + c;
                s16x8 vf = lds_frag(Vlds + d * 512, kk * 32 + col0, (d & 7) << 3);
                cacc[dt] = __builtin_amdgcn_mfma_f32_16x16x32_bf16(pf.v, vf, cacc[dt], 0, 0, 0);
            }
        }

        // ctx[b][q = qp*128 + wave*16 + 4g + j][h*64 + dt*16 + c]  (bf16)
        unsigned short* crow = ctx + ((size_t)b * 512 + qp * 128 + wave * 16) * 512 + h * 64;
#pragma unroll
        for (int dt = 0; dt < 4; dt++)
#pragma unroll
            for (int j = 0; j < 4; j++)
                crow[(size_t)(g * 4 + j) * 512 + dt * 16 + c] = f2bf(cacc[dt][j]);
    }
}

// ---------------- Kernel 2: out = LN(ctx @ W_fc + input_Q) ----------------
__global__ __launch_bounds__(256, 2) void ffn_ln_kernel(
    const unsigned short* __restrict__ ctx,    // [16384][512] bf16
    const unsigned short* __restrict__ Wtfc,   // [128 n][512 k] bf16
    const float* __restrict__ inQ,             // [16384][128] fp32
    float* __restrict__ out) {                 // [16384][128] fp32
    __shared__ float lnbuf[64][132];
    const int lane = threadIdx.x & 63;
    const int wave = threadIdx.x >> 6;
    const int g = lane >> 4, c = lane & 15;
    const int row0 = blockIdx.x * 64;

    f32x4 acc[4][2];
#pragma unroll
    for (int mt = 0; mt < 4; mt++)
#pragma unroll
        for (int nt = 0; nt < 2; nt++) acc[mt][nt] = f32x4{0.f, 0.f, 0.f, 0.f};

#pragma unroll
    for (int ks = 0; ks < 16; ks++) {
        s16x8 af[4], bf[2];
#pragma unroll
        for (int mt = 0; mt < 4; mt++) {
            const unsigned short* p = ctx + (size_t)(row0 + mt * 16 + c) * 512 + ks * 32 + 4 * g;
            union { s16x8 v; u16x4 h[2]; } u;
            u.h[0] = *reinterpret_cast<const u16x4*>(p);
            u.h[1] = *reinterpret_cast<const u16x4*>(p + 16);
            af[mt] = u.v;
        }
#pragma unroll
        for (int nt = 0; nt < 2; nt++) {
            const unsigned short* p = Wtfc + (size_t)(wave * 32 + nt * 16 + c) * 512 + ks * 32 + 4 * g;
            union { s16x8 v; u16x4 h[2]; } u;
            u.h[0] = *reinterpret_cast<const u16x4*>(p);
            u.h[1] = *reinterpret_cast<const u16x4*>(p + 16);
            bf[nt] = u.v;
        }
#pragma unroll
        for (int mt = 0; mt < 4; mt++)
#pragma unroll
            for (int nt = 0; nt < 2; nt++)
                acc[mt][nt] = __builtin_amdgcn_mfma_f32_16x16x32_bf16(af[mt], bf[nt], acc[mt][nt], 0, 0, 0);
    }

#pragma unroll
    for (int mt = 0; mt < 4; mt++)
#pragma unroll
        for (int nt = 0; nt < 2; nt++)
#pragma unroll
            for (int j = 0; j < 4; j++)
                lnbuf[mt * 16 + g * 4 + j][wave * 32 + nt * 16 + c] = acc[mt][nt][j];
    __syncthreads();

    const int r = threadIdx.x >> 2;
    const int seg = threadIdx.x & 3;
    const int grow = row0 + r;
    float x[32];
    float s1 = 0.f, s2 = 0.f;
#pragma unroll
    for (int i4 = 0; i4 < 8; i4++) {
        float4 q4 = *reinterpret_cast<const float4*>(inQ + (size_t)grow * 128 + seg * 32 + i4 * 4);
        float xs[4] = {q4.x, q4.y, q4.z, q4.w};
#pragma unroll
        for (int k = 0; k < 4; k++) {
            float xv = lnbuf[r][seg * 32 + i4 * 4 + k] + xs[k];
            x[i4 * 4 + k] = xv;
            s1 += xv;
            s2 += xv * xv;
        }
    }
    s1 += __shfl_xor(s1, 1); s1 += __shfl_xor(s1, 2);
    s2 += __shfl_xor(s2, 1); s2 += __shfl_xor(s2, 2);
    const float mu = s1 * (1.0f / 128.0f);
    const float var = s2 * (1.0f / 128.0f) - mu * mu;
    const float rs = rsqrtf(var + 1e-5f);
#pragma unroll
    for (int i = 0; i < 8; i++) {
        float4 o;
        o.x = (x[i * 4 + 0] - mu) * rs;
        o.y = (x[i * 4 + 1] - mu) * rs;
        o.z = (x[i * 4 + 2] - mu) * rs;
        o.w = (x[i * 4 + 3] - mu) * rs;
        *reinterpret_cast<float4*>(out + (size_t)grow * 128 + seg * 32 + i * 4) = o;
    }
}

// ---------------- launch ----------------
extern "C" void kernel_launch(void* const* d_in, const int* in_sizes, int n_in,
                              void* d_out, int out_size, void* d_ws, size_t ws_size,
                              hipStream_t stream) {
    const float* inQ = (const float*)d_in[0];
    const float* inK = (const float*)d_in[1];
    const float* inV = (const float*)d_in[2];
    const int*   msk = (const int*)d_in[3];
    const float* wq  = (const float*)d_in[4];
    const float* wk  = (const float*)d_in[5];
    const float* wv  = (const float*)d_in[6];
    const float* wfc = (const float*)d_in[7];

    float* out  = (float*)d_out;                           // [32][512][128] fp32
    float* attn = out + (size_t)BATCH * SEQ * DMODEL;      // [32][8][512][512] fp32

    // ws: Wtfc bf16 128KB + ctx bf16 16MB + mask bits 1MB  (~17.9MB)
    unsigned short* ws   = (unsigned short*)d_ws;
    unsigned short* Wtfc = ws;                              // [128][512]
    unsigned short* ctx  = ws + 65536;                      // [16384][512]
    unsigned long long* mbits = (unsigned long long*)(ws + 65536 + (size_t)16384 * 512);

    hipLaunchKernelGGL(wtrans_fc_kernel, dim3(8), dim3(256), 0, stream, wfc, Wtfc);
    hipLaunchKernelGGL(mask_bitpack_kernel, dim3(2048), dim3(256), 0, stream, msk, mbits);
    hipLaunchKernelGGL(attn_mega_kernel, dim3(256), dim3(512), 0, stream,
                       inQ, inK, inV, wq, wk, wv, mbits, attn, ctx);
    hipLaunchKernelGGL(ffn_ln_kernel, dim3(256), dim3(256), 0, stream, ctx, Wtfc, inQ, out);
}

// Round 7
// 385.898 us; speedup vs baseline: 1.1020x; 1.1020x over previous
//
#include <hip/hip_runtime.h>
#include <hip/hip_bf16.h>
#include <stdint.h>

#define BATCH   32
#define SEQ     512
#define DMODEL  128
#define NHEADS  8
#define DHEAD   64
#define NEGV    -1e9f

using f32x4 = __attribute__((ext_vector_type(4))) float;
using s16x8 = __attribute__((ext_vector_type(8))) short;
using u16x4 = __attribute__((ext_vector_type(4))) unsigned short;
using u16x8 = __attribute__((ext_vector_type(8))) unsigned short;

__device__ __forceinline__ unsigned short f2bf(float f) {
    union { float f; unsigned int i; } w; w.f = f;
    unsigned int u = w.i;
    u += 0x7fffu + ((u >> 16) & 1u);   // RNE
    return (unsigned short)(u >> 16);
}
__device__ __forceinline__ s16x8 fragf(const float* p0, const float* p1) {
    float4 a = *reinterpret_cast<const float4*>(p0);
    float4 b = *reinterpret_cast<const float4*>(p1);
    union { s16x8 v; unsigned short e[8]; } u;
    u.e[0] = f2bf(a.x); u.e[1] = f2bf(a.y); u.e[2] = f2bf(a.z); u.e[3] = f2bf(a.w);
    u.e[4] = f2bf(b.x); u.e[5] = f2bf(b.y); u.e[6] = f2bf(b.z); u.e[7] = f2bf(b.w);
    return u.v;
}
__device__ __forceinline__ s16x8 frag8(const unsigned short* p0, const unsigned short* p1) {
    union { s16x8 v; u16x4 h[2]; } u;
    u.h[0] = *reinterpret_cast<const u16x4*>(p0);
    u.h[1] = *reinterpret_cast<const u16x4*>(p1);
    return u.v;
}
__device__ __forceinline__ s16x8 lds_frag(const unsigned short* row_base, int col0, int swz) {
    union { s16x8 v; u16x4 h[2]; } u;
    u.h[0] = *reinterpret_cast<const u16x4*>(row_base + ((col0) ^ swz));
    u.h[1] = *reinterpret_cast<const u16x4*>(row_base + ((col0 + 16) ^ swz));
    return u.v;
}

// ---------------- Kernel 0a: transpose W_fc and W_Q (fp32 -> bf16) ----------------
// blocks 0..7: W_fc [512][128] -> Wtfc [128][512]; blocks 8..15: W_Q [128][512] -> WQt [512][128]
__global__ void wtrans_kernel(const float* __restrict__ wfc, const float* __restrict__ wq,
                              unsigned short* __restrict__ Wtfc, unsigned short* __restrict__ WQt) {
    const int m = blockIdx.x;
    if (m < 8) {
        const int i0 = m * 8192;
        for (int i = i0 + threadIdx.x; i < i0 + 8192; i += 256) {
            int k = i >> 7, n = i & 127;
            Wtfc[(size_t)n * 512 + k] = f2bf(wfc[i]);
        }
    } else {
        const int i0 = (m - 8) * 8192;
        for (int i = i0 + threadIdx.x; i < i0 + 8192; i += 256) {
            int k = i >> 9, n = i & 511;
            WQt[(size_t)n * 128 + k] = f2bf(wq[i]);
        }
    }
}

// ---------------- Kernel 0b: mask int32 -> bitpack ----------------
__global__ void mask_bitpack_kernel(const int* __restrict__ mask,
                                    unsigned long long* __restrict__ bits) {
    const int wave = threadIdx.x >> 6, lane = threadIdx.x & 63;
    const int wid0 = (blockIdx.x * 4 + wave) * 16;
#pragma unroll
    for (int i = 0; i < 16; i++) {
        const int w = wid0 + i;
        int v = mask[(size_t)w * 64 + lane];
        unsigned long long bb = __ballot(v != 0);
        if (lane == 0) bits[w] = bb;
    }
}

// ---------------- Kernel 1: K/V projection into ws (bf16) ----------------
// blockIdx.x = bh, blockIdx.y: 0 -> Kp[bh][s][64], 1 -> Vt[bh][64][s]
__global__ __launch_bounds__(512, 2) void proj_kernel(
    const float* __restrict__ inK, const float* __restrict__ inV,
    const float* __restrict__ WK, const float* __restrict__ WV,
    unsigned short* __restrict__ Kp, unsigned short* __restrict__ Vt) {
    __shared__ unsigned short Wt[64 * 128];
    const int tid = threadIdx.x;
    const int lane = tid & 63;
    const int wave = tid >> 6;
    const int g = lane >> 4, c = lane & 15;
    const int bh = blockIdx.x;
    const int b = bh >> 3, h = bh & 7;
    const int col0 = 4 * g;
    const int vmode = blockIdx.y;
    const float* X = vmode ? inV : inK;
    const float* W = vmode ? WV : WK;

    for (int i = tid; i < 8192; i += 512) {
        int k = i >> 6, d = i & 63;
        Wt[d * 128 + (k ^ ((d & 7) << 3))] = f2bf(W[(size_t)k * 512 + h * 64 + d]);
    }
    __syncthreads();

    f32x4 a4[4][4];   // [st][dt]
#pragma unroll
    for (int st = 0; st < 4; st++)
#pragma unroll
        for (int dt = 0; dt < 4; dt++) a4[st][dt] = f32x4{0.f, 0.f, 0.f, 0.f};
#pragma unroll
    for (int ks = 0; ks < 4; ks++) {
        s16x8 xf[4], wt[4];
#pragma unroll
        for (int st = 0; st < 4; st++) {
            const float* p = X + (size_t)(b * 512 + wave * 64 + st * 16 + c) * 128 + ks * 32 + col0;
            xf[st] = fragf(p, p + 16);
        }
#pragma unroll
        for (int dt = 0; dt < 4; dt++) {
            int row = dt * 16 + c;
            wt[dt] = lds_frag(Wt + row * 128, ks * 32 + col0, (row & 7) << 3);
        }
        if (!vmode) {
#pragma unroll
            for (int st = 0; st < 4; st++)
#pragma unroll
                for (int dt = 0; dt < 4; dt++)
                    a4[st][dt] = __builtin_amdgcn_mfma_f32_16x16x32_bf16(wt[dt], xf[st], a4[st][dt], 0, 0, 0);
        } else {
#pragma unroll
            for (int st = 0; st < 4; st++)
#pragma unroll
                for (int dt = 0; dt < 4; dt++)
                    a4[st][dt] = __builtin_amdgcn_mfma_f32_16x16x32_bf16(xf[st], wt[dt], a4[st][dt], 0, 0, 0);
        }
    }
    if (!vmode) {
        // D[d = dt*16+col0+j][s = wave*64+st*16+c] -> Kp[bh][s][d]
#pragma unroll
        for (int st = 0; st < 4; st++) {
            const int s = wave * 64 + st * 16 + c;
#pragma unroll
            for (int dt = 0; dt < 4; dt++) {
                u16x4 o;
#pragma unroll
                for (int j = 0; j < 4; j++) o[j] = f2bf(a4[st][dt][j]);
                *reinterpret_cast<u16x4*>(Kp + ((size_t)bh * 512 + s) * 64 + dt * 16 + col0) = o;
            }
        }
    } else {
        // D[s = wave*64+st*16+col0+j][d = dt*16+c] -> Vt[bh][d][s]
#pragma unroll
        for (int dt = 0; dt < 4; dt++) {
            const int d = dt * 16 + c;
#pragma unroll
            for (int st = 0; st < 4; st++) {
                u16x4 o;
#pragma unroll
                for (int j = 0; j < 4; j++) o[j] = f2bf(a4[st][dt][j]);
                *reinterpret_cast<u16x4*>(Vt + ((size_t)bh * 64 + d) * 512 + wave * 64 + st * 16 + col0) = o;
            }
        }
    }
}

// ---------------- Kernel 2: attention, no LDS, no barriers ----------------
// grid 2048: bid -> (bh, qc); 256 threads = 4 waves x 16 q rows.
__global__ __launch_bounds__(256, 2) void attn_kernel(
    const float* __restrict__ inQ,            // [b*512][128] fp32
    const unsigned short* __restrict__ WQt,   // [512][128] bf16 (W_Q^T)
    const unsigned short* __restrict__ Kp,    // [bh][s][64] bf16
    const unsigned short* __restrict__ Vt,    // [bh][64][s] bf16
    const unsigned long long* __restrict__ mbits,
    float* __restrict__ attn_out,             // [bh][q][k] fp32
    unsigned short* __restrict__ ctx) {       // [b*512][512] bf16
    const int tid = threadIdx.x;
    const int lane = tid & 63;
    const int wave = tid >> 6;          // 0..3
    const int g = lane >> 4, c = lane & 15;
    const int col0 = 4 * g;
    const int bid = blockIdx.x;
    // bid = [qc:3][h:3][y:2][x:3]; bh fixed => bid%8 fixed => same XCD for all qc
    const int bh = (((bid & 7) * 4 + ((bid >> 3) & 3)) << 3) + ((bid >> 5) & 7);
    const int qc = bid >> 8;            // 0..7
    const int b = bh >> 3, h = bh & 7;
    const int qg = qc * 64 + wave * 16 + c;

    const unsigned short* Kb = Kp + (size_t)bh * 512 * 64;
    const unsigned short* Vb = Vt + (size_t)bh * 64 * 512;

    // mask bits for this q-row
    union { uint4 q[4]; unsigned short e[32]; } mb;
    {
        const unsigned short* mrow16 = (const unsigned short*)(mbits + ((size_t)b * 512 + qg) * 8);
        mb.q[0] = *reinterpret_cast<const uint4*>(mrow16);
        mb.q[1] = *reinterpret_cast<const uint4*>(mrow16 + 8);
        mb.q[2] = *reinterpret_cast<const uint4*>(mrow16 + 16);
        mb.q[3] = *reinterpret_cast<const uint4*>(mrow16 + 24);
    }

    // Q projection (global WQt, L2-hot)
    f32x4 qa[4];
#pragma unroll
    for (int dt = 0; dt < 4; dt++) qa[dt] = f32x4{0.f, 0.f, 0.f, 0.f};
    const float* Xq = inQ + ((size_t)b * 512 + qg) * 128;
#pragma unroll
    for (int ks = 0; ks < 4; ks++) {
        s16x8 xq = fragf(Xq + ks * 32 + col0, Xq + ks * 32 + col0 + 16);
#pragma unroll
        for (int dt = 0; dt < 4; dt++) {
            const unsigned short* wp = WQt + (size_t)(h * 64 + dt * 16 + c) * 128 + ks * 32 + col0;
            s16x8 wt = frag8(wp, wp + 16);
            qa[dt] = __builtin_amdgcn_mfma_f32_16x16x32_bf16(wt, xq, qa[dt], 0, 0, 0);
        }
    }
    s16x8 qf0, qf1;
    {
        union { s16x8 v; u16x4 h2[2]; } q0, q1;
#pragma unroll
        for (int j = 0; j < 4; j++) {
            q0.h2[0][j] = f2bf(qa[0][j]);
            q0.h2[1][j] = f2bf(qa[1][j]);
            q1.h2[0][j] = f2bf(qa[2][j]);
            q1.h2[1][j] = f2bf(qa[3][j]);
        }
        qf0 = q0.v; qf1 = q1.v;
    }

    // S^T = K * Q^T
    f32x4 acc[32];
#pragma unroll
    for (int t = 0; t < 32; t++) acc[t] = f32x4{0.f, 0.f, 0.f, 0.f};
#pragma unroll
    for (int kt = 0; kt < 32; kt++) {
        const unsigned short* Kr = Kb + (size_t)(kt * 16 + c) * 64;
        s16x8 a0 = frag8(Kr + col0, Kr + col0 + 16);
        s16x8 a1 = frag8(Kr + 32 + col0, Kr + 32 + col0 + 16);
        acc[kt] = __builtin_amdgcn_mfma_f32_16x16x32_bf16(a0, qf0, acc[kt], 0, 0, 0);
        acc[kt] = __builtin_amdgcn_mfma_f32_16x16x32_bf16(a1, qf1, acc[kt], 0, 0, 0);
    }

    // scale + mask + row max
    float m = -3.0e38f;
#pragma unroll
    for (int t = 0; t < 32; t++) {
        const unsigned nib = ((unsigned)mb.e[t]) >> col0;
        float s0 = (nib & 1u) ? NEGV : acc[t][0] * 0.125f;
        float s1 = (nib & 2u) ? NEGV : acc[t][1] * 0.125f;
        float s2 = (nib & 4u) ? NEGV : acc[t][2] * 0.125f;
        float s3 = (nib & 8u) ? NEGV : acc[t][3] * 0.125f;
        acc[t] = f32x4{s0, s1, s2, s3};
        m = fmaxf(m, fmaxf(fmaxf(s0, s1), fmaxf(s2, s3)));
    }
    m = fmaxf(m, __shfl_xor(m, 16));
    m = fmaxf(m, __shfl_xor(m, 32));

    float sum = 0.f;
#pragma unroll
    for (int t = 0; t < 32; t++) {
#pragma unroll
        for (int j = 0; j < 4; j++) {
            float e = __expf(acc[t][j] - m);
            acc[t][j] = e;
            sum += e;
        }
    }
    sum += __shfl_xor(sum, 16);
    sum += __shfl_xor(sum, 32);
    const float inv = 1.0f / sum;

    float* arow = attn_out + ((size_t)bh * 512 + qg) * 512;
    f32x4 cacc[4];
#pragma unroll
    for (int dt = 0; dt < 4; dt++) cacc[dt] = f32x4{0.f, 0.f, 0.f, 0.f};

#pragma unroll
    for (int kk = 0; kk < 16; kk++) {
        float4 flo, fhi;
        u16x4 lo, hi;
        flo.x = acc[2 * kk][0] * inv;  flo.y = acc[2 * kk][1] * inv;
        flo.z = acc[2 * kk][2] * inv;  flo.w = acc[2 * kk][3] * inv;
        fhi.x = acc[2 * kk + 1][0] * inv; fhi.y = acc[2 * kk + 1][1] * inv;
        fhi.z = acc[2 * kk + 1][2] * inv; fhi.w = acc[2 * kk + 1][3] * inv;
        lo[0] = f2bf(flo.x); lo[1] = f2bf(flo.y); lo[2] = f2bf(flo.z); lo[3] = f2bf(flo.w);
        hi[0] = f2bf(fhi.x); hi[1] = f2bf(fhi.y); hi[2] = f2bf(fhi.z); hi[3] = f2bf(fhi.w);
        *reinterpret_cast<float4*>(arow + kk * 32 + col0)      = flo;
        *reinterpret_cast<float4*>(arow + kk * 32 + 16 + col0) = fhi;
        union { s16x8 v; u16x4 h2[2]; } pf;
        pf.h2[0] = lo; pf.h2[1] = hi;
#pragma unroll
        for (int dt = 0; dt < 4; dt++) {
            const unsigned short* vp = Vb + (size_t)(dt * 16 + c) * 512 + kk * 32 + col0;
            s16x8 vf = frag8(vp, vp + 16);
            cacc[dt] = __builtin_amdgcn_mfma_f32_16x16x32_bf16(pf.v, vf, cacc[dt], 0, 0, 0);
        }
    }

    unsigned short* crow = ctx + ((size_t)b * 512 + qc * 64 + wave * 16) * 512 + h * 64;
#pragma unroll
    for (int dt = 0; dt < 4; dt++)
#pragma unroll
        for (int j = 0; j < 4; j++)
            crow[(size_t)(g * 4 + j) * 512 + dt * 16 + c] = f2bf(cacc[dt][j]);
}

// ---------------- Fallback: round-6 mega kernel (used if ws_size too small) ----------------
__global__ __launch_bounds__(512, 1) void attn_mega_kernel(
    const float* __restrict__ inQ, const float* __restrict__ inK, const float* __restrict__ inV,
    const float* __restrict__ WQ, const float* __restrict__ WK, const float* __restrict__ WV,
    const unsigned long long* __restrict__ mbits,
    float* __restrict__ attn_out, unsigned short* __restrict__ ctx) {
    __shared__ unsigned short Klds[512 * 64];
    __shared__ unsigned short Vlds[64 * 512];
    __shared__ unsigned short Wt[64 * 128];
    const int tid = threadIdx.x;
    const int lane = tid & 63;
    const int wave = tid >> 6;
    const int g = lane >> 4, c = lane & 15;
    const int bid = blockIdx.x;
    const int bh = (((bid & 7) * 4 + ((bid >> 3) & 3)) << 3) + (bid >> 5);
    const int b = bh >> 3, h = bh & 7;
    const int col0 = 4 * g;

    for (int i = tid; i < 8192; i += 512) {
        int k = i >> 6, d = i & 63;
        Wt[d * 128 + (k ^ ((d & 7) << 3))] = f2bf(WK[(size_t)k * 512 + h * 64 + d]);
    }
    __syncthreads();
    {
        f32x4 ka[4][4];
#pragma unroll
        for (int st = 0; st < 4; st++)
#pragma unroll
            for (int dt = 0; dt < 4; dt++) ka[st][dt] = f32x4{0.f, 0.f, 0.f, 0.f};
#pragma unroll
        for (int ks = 0; ks < 4; ks++) {
            s16x8 xk[4], wt[4];
#pragma unroll
            for (int st = 0; st < 4; st++) {
                const float* p = inK + (size_t)(b * 512 + wave * 64 + st * 16 + c) * 128 + ks * 32 + col0;
                xk[st] = fragf(p, p + 16);
            }
#pragma unroll
            for (int dt = 0; dt < 4; dt++) {
                int row = dt * 16 + c;
                wt[dt] = lds_frag(Wt + row * 128, ks * 32 + col0, (row & 7) << 3);
            }
#pragma unroll
            for (int st = 0; st < 4; st++)
#pragma unroll
                for (int dt = 0; dt < 4; dt++)
                    ka[st][dt] = __builtin_amdgcn_mfma_f32_16x16x32_bf16(wt[dt], xk[st], ka[st][dt], 0, 0, 0);
        }
#pragma unroll
        for (int st = 0; st < 4; st++) {
            const int s = wave * 64 + st * 16 + c;
            const int swz = (s & 7) << 3;
#pragma unroll
            for (int dt = 0; dt < 4; dt++) {
                u16x4 o;
#pragma unroll
                for (int j = 0; j < 4; j++) o[j] = f2bf(ka[st][dt][j]);
                *reinterpret_cast<u16x4*>(Klds + s * 64 + ((dt * 16 + col0) ^ swz)) = o;
            }
        }
    }
    __syncthreads();
    for (int i = tid; i < 8192; i += 512) {
        int k = i >> 6, d = i & 63;
        Wt[d * 128 + (k ^ ((d & 7) << 3))] = f2bf(WV[(size_t)k * 512 + h * 64 + d]);
    }
    __syncthreads();
    {
        f32x4 va[4][4];
#pragma unroll
        for (int st = 0; st < 4; st++)
#pragma unroll
            for (int dt = 0; dt < 4; dt++) va[st][dt] = f32x4{0.f, 0.f, 0.f, 0.f};
#pragma unroll
        for (int ks = 0; ks < 4; ks++) {
            s16x8 xv[4], wt[4];
#pragma unroll
            for (int st = 0; st < 4; st++) {
                const float* p = inV + (size_t)(b * 512 + wave * 64 + st * 16 + c) * 128 + ks * 32 + col0;
                xv[st] = fragf(p, p + 16);
            }
#pragma unroll
            for (int dt = 0; dt < 4; dt++) {
                int row = dt * 16 + c;
                wt[dt] = lds_frag(Wt + row * 128, ks * 32 + col0, (row & 7) << 3);
            }
#pragma unroll
            for (int st = 0; st < 4; st++)
#pragma unroll
                for (int dt = 0; dt < 4; dt++)
                    va[st][dt] = __builtin_amdgcn_mfma_f32_16x16x32_bf16(xv[st], wt[dt], va[st][dt], 0, 0, 0);
        }
#pragma unroll
        for (int dt = 0; dt < 4; dt++) {
            const int d = dt * 16 + c;
            const int swz = (d & 7) << 3;
#pragma unroll
            for (int st = 0; st < 4; st++) {
                u16x4 o;
#pragma unroll
                for (int j = 0; j < 4; j++) o[j] = f2bf(va[st][dt][j]);
                *reinterpret_cast<u16x4*>(Vlds + d * 512 + ((wave * 64 + st * 16 + col0) ^ swz)) = o;
            }
        }
    }
    __syncthreads();
    for (int i = tid; i < 8192; i += 512) {
        int k = i >> 6, d = i & 63;
        Wt[d * 128 + (k ^ ((d & 7) << 3))] = f2bf(WQ[(size_t)k * 512 + h * 64 + d]);
    }
    __syncthreads();

    for (int qp = 0; qp < 4; qp++) {
        const int qg = qp * 128 + wave * 16 + c;
        union { uint4 q[4]; unsigned short e[32]; } mb;
        {
            const unsigned short* mrow16 = (const unsigned short*)(mbits + ((size_t)b * 512 + qg) * 8);
            mb.q[0] = *reinterpret_cast<const uint4*>(mrow16);
            mb.q[1] = *reinterpret_cast<const uint4*>(mrow16 + 8);
            mb.q[2] = *reinterpret_cast<const uint4*>(mrow16 + 16);
            mb.q[3] = *reinterpret_cast<const uint4*>(mrow16 + 24);
        }
        f32x4 qa[4];
#pragma unroll
        for (int dt = 0; dt < 4; dt++) qa[dt] = f32x4{0.f, 0.f, 0.f, 0.f};
        const float* Xq = inQ + ((size_t)b * 512 + qg) * 128;
#pragma unroll
        for (int ks = 0; ks < 4; ks++) {
            s16x8 xq = fragf(Xq + ks * 32 + col0, Xq + ks * 32 + col0 + 16);
#pragma unroll
            for (int dt = 0; dt < 4; dt++) {
                int row = dt * 16 + c;
                s16x8 wt = lds_frag(Wt + row * 128, ks * 32 + col0, (row & 7) << 3);
                qa[dt] = __builtin_amdgcn_mfma_f32_16x16x32_bf16(wt, xq, qa[dt], 0, 0, 0);
            }
        }
        s16x8 qf0, qf1;
        {
            union { s16x8 v; u16x4 h2[2]; } q0, q1;
#pragma unroll
            for (int j = 0; j < 4; j++) {
                q0.h2[0][j] = f2bf(qa[0][j]);
                q0.h2[1][j] = f2bf(qa[1][j]);
                q1.h2[0][j] = f2bf(qa[2][j]);
                q1.h2[1][j] = f2bf(qa[3][j]);
            }
            qf0 = q0.v; qf1 = q1.v;
        }
        f32x4 acc[32];
#pragma unroll
        for (int t = 0; t < 32; t++) acc[t] = f32x4{0.f, 0.f, 0.f, 0.f};
#pragma unroll
        for (int kt = 0; kt < 32; kt++) {
            const int row = kt * 16 + c;
            const int swz = (row & 7) << 3;
            const unsigned short* rb = Klds + row * 64;
            s16x8 a0 = lds_frag(rb, col0, swz);
            s16x8 a1 = lds_frag(rb, 32 + col0, swz);
            acc[kt] = __builtin_amdgcn_mfma_f32_16x16x32_bf16(a0, qf0, acc[kt], 0, 0, 0);
            acc[kt] = __builtin_amdgcn_mfma_f32_16x16x32_bf16(a1, qf1, acc[kt], 0, 0, 0);
        }
        float m = -3.0e38f;
#pragma unroll
        for (int t = 0; t < 32; t++) {
            const unsigned nib = ((unsigned)mb.e[t]) >> col0;
            float s0 = (nib & 1u) ? NEGV : acc[t][0] * 0.125f;
            float s1 = (nib & 2u) ? NEGV : acc[t][1] * 0.125f;
            float s2 = (nib & 4u) ? NEGV : acc[t][2] * 0.125f;
            float s3 = (nib & 8u) ? NEGV : acc[t][3] * 0.125f;
            acc[t] = f32x4{s0, s1, s2, s3};
            m = fmaxf(m, fmaxf(fmaxf(s0, s1), fmaxf(s2, s3)));
        }
        m = fmaxf(m, __shfl_xor(m, 16));
        m = fmaxf(m, __shfl_xor(m, 32));
        float sum = 0.f;
#pragma unroll
        for (int t = 0; t < 32; t++) {
#pragma unroll
            for (int j = 0; j < 4; j++) {
                float e = __expf(acc[t][j] - m);
                acc[t][j] = e;
                sum += e;
            }
        }
        sum += __shfl_xor(sum, 16);
        sum += __shfl_xor(sum, 32);
        const float inv = 1.0f / sum;
        float* arow = attn_out + ((size_t)bh * 512 + qg) * 512;
        f32x4 cacc[4];
#pragma unroll
        for (int dt = 0; dt < 4; dt++) cacc[dt] = f32x4{0.f, 0.f, 0.f, 0.f};
#pragma unroll
        for (int kk = 0; kk < 16; kk++) {
            float4 flo, fhi;
            u16x4 lo, hi;
            flo.x = acc[2 * kk][0] * inv;  flo.y = acc[2 * kk][1] * inv;
            flo.z = acc[2 * kk][2] * inv;  flo.w = acc[2 * kk][3] * inv;
            fhi.x = acc[2 * kk + 1][0] * inv; fhi.y = acc[2 * kk + 1][1] * inv;
            fhi.z = acc[2 * kk + 1][2] * inv; fhi.w = acc[2 * kk + 1][3] * inv;
            lo[0] = f2bf(flo.x); lo[1] = f2bf(flo.y); lo[2] = f2bf(flo.z); lo[3] = f2bf(flo.w);
            hi[0] = f2bf(fhi.x); hi[1] = f2bf(fhi.y); hi[2] = f2bf(fhi.z); hi[3] = f2bf(fhi.w);
            *reinterpret_cast<float4*>(arow + kk * 32 + col0)      = flo;
            *reinterpret_cast<float4*>(arow + kk * 32 + 16 + col0) = fhi;
            union { s16x8 v; u16x4 h2[2]; } pf;
            pf.h2[0] = lo; pf.h2[1] = hi;
#pragma unroll
            for (int dt = 0; dt < 4; dt++) {
                const int d = dt * 16 + c;
                s16x8 vf = lds_frag(Vlds + d * 512, kk * 32 + col0, (d & 7) << 3);
                cacc[dt] = __builtin_amdgcn_mfma_f32_16x16x32_bf16(pf.v, vf, cacc[dt], 0, 0, 0);
            }
        }
        unsigned short* crow = ctx + ((size_t)b * 512 + qp * 128 + wave * 16) * 512 + h * 64;
#pragma unroll
        for (int dt = 0; dt < 4; dt++)
#pragma unroll
            for (int j = 0; j < 4; j++)
                crow[(size_t)(g * 4 + j) * 512 + dt * 16 + c] = f2bf(cacc[dt][j]);
    }
}

// ---------------- Kernel 3: out = LN(ctx @ W_fc + input_Q) ----------------
__global__ __launch_bounds__(256, 2) void ffn_ln_kernel(
    const unsigned short* __restrict__ ctx,
    const unsigned short* __restrict__ Wtfc,
    const float* __restrict__ inQ,
    float* __restrict__ out) {
    __shared__ float lnbuf[64][132];
    const int lane = threadIdx.x & 63;
    const int wave = threadIdx.x >> 6;
    const int g = lane >> 4, c = lane & 15;
    const int row0 = blockIdx.x * 64;

    f32x4 acc[4][2];
#pragma unroll
    for (int mt = 0; mt < 4; mt++)
#pragma unroll
        for (int nt = 0; nt < 2; nt++) acc[mt][nt] = f32x4{0.f, 0.f, 0.f, 0.f};
#pragma unroll
    for (int ks = 0; ks < 16; ks++) {
        s16x8 af[4], bf[2];
#pragma unroll
        for (int mt = 0; mt < 4; mt++) {
            const unsigned short* p = ctx + (size_t)(row0 + mt * 16 + c) * 512 + ks * 32 + 4 * g;
            af[mt] = frag8(p, p + 16);
        }
#pragma unroll
        for (int nt = 0; nt < 2; nt++) {
            const unsigned short* p = Wtfc + (size_t)(wave * 32 + nt * 16 + c) * 512 + ks * 32 + 4 * g;
            bf[nt] = frag8(p, p + 16);
        }
#pragma unroll
        for (int mt = 0; mt < 4; mt++)
#pragma unroll
            for (int nt = 0; nt < 2; nt++)
                acc[mt][nt] = __builtin_amdgcn_mfma_f32_16x16x32_bf16(af[mt], bf[nt], acc[mt][nt], 0, 0, 0);
    }
#pragma unroll
    for (int mt = 0; mt < 4; mt++)
#pragma unroll
        for (int nt = 0; nt < 2; nt++)
#pragma unroll
            for (int j = 0; j < 4; j++)
                lnbuf[mt * 16 + g * 4 + j][wave * 32 + nt * 16 + c] = acc[mt][nt][j];
    __syncthreads();

    const int r = threadIdx.x >> 2;
    const int seg = threadIdx.x & 3;
    const int grow = row0 + r;
    float x[32];
    float s1 = 0.f, s2 = 0.f;
#pragma unroll
    for (int i4 = 0; i4 < 8; i4++) {
        float4 q4 = *reinterpret_cast<const float4*>(inQ + (size_t)grow * 128 + seg * 32 + i4 * 4);
        float xs[4] = {q4.x, q4.y, q4.z, q4.w};
#pragma unroll
        for (int k = 0; k < 4; k++) {
            float xv = lnbuf[r][seg * 32 + i4 * 4 + k] + xs[k];
            x[i4 * 4 + k] = xv;
            s1 += xv;
            s2 += xv * xv;
        }
    }
    s1 += __shfl_xor(s1, 1); s1 += __shfl_xor(s1, 2);
    s2 += __shfl_xor(s2, 1); s2 += __shfl_xor(s2, 2);
    const float mu = s1 * (1.0f / 128.0f);
    const float var = s2 * (1.0f / 128.0f) - mu * mu;
    const float rs = rsqrtf(var + 1e-5f);
#pragma unroll
    for (int i = 0; i < 8; i++) {
        float4 o;
        o.x = (x[i * 4 + 0] - mu) * rs;
        o.y = (x[i * 4 + 1] - mu) * rs;
        o.z = (x[i * 4 + 2] - mu) * rs;
        o.w = (x[i * 4 + 3] - mu) * rs;
        *reinterpret_cast<float4*>(out + (size_t)grow * 128 + seg * 32 + i * 4) = o;
    }
}

// ---------------- launch ----------------
extern "C" void kernel_launch(void* const* d_in, const int* in_sizes, int n_in,
                              void* d_out, int out_size, void* d_ws, size_t ws_size,
                              hipStream_t stream) {
    const float* inQ = (const float*)d_in[0];
    const float* inK = (const float*)d_in[1];
    const float* inV = (const float*)d_in[2];
    const int*   msk = (const int*)d_in[3];
    const float* wq  = (const float*)d_in[4];
    const float* wk  = (const float*)d_in[5];
    const float* wv  = (const float*)d_in[6];
    const float* wfc = (const float*)d_in[7];

    float* out  = (float*)d_out;
    float* attn = out + (size_t)BATCH * SEQ * DMODEL;

    // ws layout (u16 units):
    unsigned short* ws   = (unsigned short*)d_ws;
    unsigned short* Wtfc = ws;                                  // 65536
    unsigned short* WQt  = ws + 65536;                          // 65536
    unsigned short* ctx  = ws + 131072;                         // 8388608
    unsigned long long* mbits = (unsigned long long*)(ws + 131072 + 8388608);  // 1MB
    unsigned short* Kp   = ws + 131072 + 8388608 + 524288;      // 8388608
    unsigned short* Vt   = Kp + 8388608;                        // 8388608
    const size_t need_split = (size_t)(131072 + 8388608 + 524288 + 2 * 8388608) * 2;

    hipLaunchKernelGGL(wtrans_kernel, dim3(16), dim3(256), 0, stream, wfc, wq, Wtfc, WQt);
    hipLaunchKernelGGL(mask_bitpack_kernel, dim3(2048), dim3(256), 0, stream, msk, mbits);

    if (ws_size >= need_split) {
        hipLaunchKernelGGL(proj_kernel, dim3(256, 2), dim3(512), 0, stream,
                           inK, inV, wk, wv, Kp, Vt);
        hipLaunchKernelGGL(attn_kernel, dim3(2048), dim3(256), 0, stream,
                           inQ, WQt, Kp, Vt, mbits, attn, ctx);
    } else {
        hipLaunchKernelGGL(attn_mega_kernel, dim3(256), dim3(512), 0, stream,
                           inQ, inK, inV, wq, wk, wv, mbits, attn, ctx);
    }
    hipLaunchKernelGGL(ffn_ln_kernel, dim3(256), dim3(256), 0, stream, ctx, Wtfc, inQ, out);
}